// Round 14
// baseline (78.713 us; speedup 1.0000x reference)
//
#include <hip/hip_runtime.h>
#include <hip/hip_bf16.h>
#include <math.h>

// Problem dims (fixed by setup_inputs)
#define BB 4
#define LLEN 4096
#define HH 8
#define MM 256
#define KX 96
#define EE 80          // padded c-dim: 64 v + 1 ones + 15 zero
#define NTOK 16384
#define NORM 0.35355339059327373f   // 64^-0.25 (folded into projF cols 0..63)
#define NORM2 0.125f                // NORM^2
#define LN16 2.7725887222397811f    // ln(sqrt(256)) folded into h
#define EPSV 1e-6f
#define TWO_PI_F 6.283185307179586f
#define NSPLIT 8

typedef __attribute__((ext_vector_type(8))) short s16x8;   // 8 bf16 (4 VGPRs)
typedef __attribute__((ext_vector_type(4))) short s16x4;   // 4 bf16 (2 VGPRs)
typedef __attribute__((ext_vector_type(4))) float f32x4;
typedef __attribute__((ext_vector_type(4))) unsigned int u32x4;

#define MFMA16(A,B,C) __builtin_amdgcn_mfma_f32_16x16x32_bf16(A,B,C,0,0,0)

static __device__ __forceinline__ unsigned short f2bf(float f) {
  union { float f; unsigned int u; } v; v.f = f;
  unsigned int r = v.u + 0x7FFFu + ((v.u >> 16) & 1u);   // RNE
  return (unsigned short)(r >> 16);
}
static __device__ __forceinline__ unsigned int pk2(float lo, float hi) {
  __hip_bfloat162 h = __float22bfloat162_rn(make_float2(lo, hi));
  union { __hip_bfloat162 h; unsigned int u; } c; c.h = h;
  return c.u;
}
static __device__ __forceinline__ s16x8 cat4(s16x4 a, s16x4 b) {
  s16x8 r;
  r[0]=a[0]; r[1]=a[1]; r[2]=a[2]; r[3]=a[3];
  r[4]=b[0]; r[5]=b[1]; r[6]=b[2]; r[7]=b[3];
  return r;
}

// ---- workspace byte offsets ----
#define OFF_PROJF 0u
#define OFF_PARTS 524288u
#define OFF_B1F   (OFF_PARTS + 20971520u)   // NSPLIT=8 parts

// ---------------------------------------------------------------------------
// projF fragment-major: chunk c = mt*3+xs, lane l, j:
//   projLogical[(l&15)+16mt][32xs+8(l>>4)+j]; cols: 0..63 proj*NORM,
//   64..71 proj, 72 = -1 (hq fold), 73..95 = 0.
// ---------------------------------------------------------------------------
__global__ __launch_bounds__(256) void prep_projF(const float* __restrict__ proj,
                                                  unsigned short* __restrict__ projF) {
  int t = threadIdx.x;
  int l = t & 63, grp = t >> 6;
  int l15 = l & 15, l4 = l >> 4;
  for (int c = grp; c < 48; c += 4) {
    int mt = c / 3, xs = c % 3;
    int m = l15 + 16 * mt;
    s16x8 o;
#pragma unroll
    for (int j = 0; j < 8; ++j) {
      int d = 32 * xs + 8 * l4 + j;
      unsigned short u;
      if (d < 64)       u = f2bf(proj[m * 72 + d] * NORM);
      else if (d < 72)  u = f2bf(proj[m * 72 + d]);
      else if (d == 72) u = 0xBF80;  // bf16(-1)
      else              u = 0;
      o[j] = (short)u;
    }
    *reinterpret_cast<s16x8*>(projF + ((size_t)c * 64 + l) * 8) = o;
  }
}

// ---------------------------------------------------------------------------
// F1: fused {ks->bf16 + fourier + hk} + phi_k GEMM + exp + buf1 GEMM with
// V via ds_read_b64_tr_b16 (slot model: col = (A>>3)&15, A = base+128l4+8l15).
// 1024 threads (16 waves, 1 m-tile each), grid (32 bh, 8 splits).
// ---------------------------------------------------------------------------
__global__ __launch_bounds__(1024, 1) void f1_k(
    const float* __restrict__ ks, const float* __restrict__ ks_s,
    const float* __restrict__ vs, const float* __restrict__ W,
    const unsigned short* __restrict__ projF,
    float* __restrict__ parts) {
  __shared__ unsigned short pf_lds[24576];             // 48 KB
  __shared__ alignas(16) unsigned char sbuf[2][12288]; // [0..8191]=ks tile, [8192..]=v tile
  __shared__ alignas(16) float hk_sh[2][32];

  int bh = blockIdx.x, split = blockIdx.y;
  int b = bh >> 3, h = bh & 7;
  int tid = threadIdx.x;
  int w = tid >> 6, l = tid & 63;
  int l15 = l & 15, l4 = l >> 4;
  int kbase = split * 512;
  int row = tid >> 4, seg = tid & 15;   // staging roles, tid<512
  int s4 = (row & 7) << 4;

  const float* ksb = ks + ((size_t)(b * LLEN + kbase) * HH + h) * 64;  // stride 512 f32/key
  const float* vsb = vs + ((size_t)(b * LLEN + kbase) * HH + h) * 64;
  const float* kss = ks_s + (size_t)b * LLEN + kbase;

  float wv = 0.f; bool issin = false;
  if (seg < 8) { int dim = 8 * h + seg; wv = W[dim & 31] * TWO_PI_F; issin = dim < 32; }

  // v-tile write slot: [ne=seg>>2][k=row][4(seg&3)..+3]
  int vwo = 8192 + (seg >> 2) * 1024 + row * 32 + (seg & 3) * 8;

  // ---- prologue: zero upper 128B of ks rows (both bufs) + stage projF ----
  if (tid < 512) {
    int bi = tid >> 8, rem = tid & 255;
    u32x4 z = {};
    *reinterpret_cast<u32x4*>(&sbuf[bi][(rem >> 3) * 256 + 128 + (rem & 7) * 16]) = z;
  }
  {
    const u32x4* g1 = reinterpret_cast<const u32x4*>(projF);
    u32x4* s1 = reinterpret_cast<u32x4*>(pf_lds);
#pragma unroll
    for (int i = 0; i < 3; ++i) s1[i * 1024 + tid] = g1[i * 1024 + tid];
  }
  __syncthreads();
  // ---- stage tile 0: ks (+fourier+hk) and v ----
  if (tid < 512) {
    f32x4 kv = *reinterpret_cast<const f32x4*>(ksb + (size_t)row * 512 + 4 * seg);
    float part = (kv[0]*kv[0] + kv[1]*kv[1] + kv[2]*kv[2] + kv[3]*kv[3]) * NORM2;
    s16x4 o;
#pragma unroll
    for (int i = 0; i < 4; ++i) o[i] = (short)f2bf(kv[i]);
    *reinterpret_cast<s16x4*>(&sbuf[0][row * 256 + ((8 * seg) ^ s4)]) = o;
    if (seg < 8) {
      float ph = kss[row] * wv;
      float e = issin ? sinf(ph) : cosf(ph);
      part += e * e;
      *reinterpret_cast<unsigned short*>(&sbuf[0][row * 256 + ((128 + 2 * seg) ^ s4)]) = f2bf(e);
    }
#pragma unroll
    for (int m = 1; m < 16; m <<= 1) part += __shfl_xor(part, m, 64);
    if (seg == 0) hk_sh[0][row] = 0.5f * part + LN16;
    f32x4 vv = *reinterpret_cast<const f32x4*>(vsb + (size_t)row * 512 + 4 * seg);
    uint2 vp = make_uint2(pk2(vv[0], vv[1]), pk2(vv[2], vv[3]));
    *reinterpret_cast<uint2*>(&sbuf[0][vwo]) = vp;
  }
  __syncthreads();

  // constant ne=4 B-frag: c[k][e=64+l15] = (l15==0) ? 1 : 0
  s16x8 vb4 = {};
  if (l15 == 0) {
#pragma unroll
    for (int j = 0; j < 8; ++j) vb4[j] = (short)0x3F80;
  }

  f32x4 acc2[5] = {};

  for (int it = 0; it < 16; ++it) {
    int cur = it & 1, nxt = cur ^ 1;
    // issue-early: next-tile global loads
    f32x4 kvn, vvn; float svn = 0.f;
    if (it < 15 && tid < 512) {
      kvn = *reinterpret_cast<const f32x4*>(ksb + (size_t)(32 * (it + 1) + row) * 512 + 4 * seg);
      vvn = *reinterpret_cast<const f32x4*>(vsb + (size_t)(32 * (it + 1) + row) * 512 + 4 * seg);
      if (seg < 8) svn = kss[32 * (it + 1) + row];
    }

    // ---- GEMM1: P = Xk . projF^T (wave's single m-tile) ----
    f32x4 acc1_0 = {}, acc1_1 = {};
#pragma unroll
    for (int xs = 0; xs < 3; ++xs) {
      int co = (64 * xs + 16 * l4) ^ ((l15 & 7) << 4);
      s16x8 ak0 = *reinterpret_cast<const s16x8*>(&sbuf[cur][l15 * 256 + co]);
      s16x8 ak1 = *reinterpret_cast<const s16x8*>(&sbuf[cur][(16 + l15) * 256 + co]);
      s16x8 pf = *reinterpret_cast<const s16x8*>(pf_lds + ((w * 3 + xs) * 64 + l) * 8);
      acc1_0 = MFMA16(ak0, pf, acc1_0);
      acc1_1 = MFMA16(ak1, pf, acc1_1);
    }
    // ---- exp -> bf16 A-frag ----
    f32x4 hk0 = *reinterpret_cast<const f32x4*>(&hk_sh[cur][4 * l4]);
    f32x4 hk1 = *reinterpret_cast<const f32x4*>(&hk_sh[cur][16 + 4 * l4]);
    union { unsigned int u[4]; s16x8 s; } P;
    P.u[0] = pk2(__expf(acc1_0[0] - hk0[0]), __expf(acc1_0[1] - hk0[1]));
    P.u[1] = pk2(__expf(acc1_0[2] - hk0[2]), __expf(acc1_0[3] - hk0[3]));
    P.u[2] = pk2(__expf(acc1_1[0] - hk1[0]), __expf(acc1_1[1] - hk1[1]));
    P.u[3] = pk2(__expf(acc1_1[2] - hk1[2]), __expf(acc1_1[3] - hk1[3]));

    // ---- GEMM2 B-frags via HW transpose-read from v tile ----
    unsigned int va = (unsigned int)(size_t)(&sbuf[cur][8192]) + 8 * l15 + 128 * l4;
    s16x4 t0, t1, t2, t3, t4, t5, t6, t7;
    asm volatile(
        "ds_read_b64_tr_b16 %0, %8 offset:0\n\t"
        "ds_read_b64_tr_b16 %1, %8 offset:512\n\t"
        "ds_read_b64_tr_b16 %2, %8 offset:1024\n\t"
        "ds_read_b64_tr_b16 %3, %8 offset:1536\n\t"
        "ds_read_b64_tr_b16 %4, %8 offset:2048\n\t"
        "ds_read_b64_tr_b16 %5, %8 offset:2560\n\t"
        "ds_read_b64_tr_b16 %6, %8 offset:3072\n\t"
        "ds_read_b64_tr_b16 %7, %8 offset:3584"
        : "=&v"(t0), "=&v"(t1), "=&v"(t2), "=&v"(t3),
          "=&v"(t4), "=&v"(t5), "=&v"(t6), "=&v"(t7)
        : "v"(va)
        : "memory");
    asm volatile("s_waitcnt lgkmcnt(0)" ::: "memory");
    __builtin_amdgcn_sched_barrier(0);

    acc2[0] = MFMA16(P.s, cat4(t0, t1), acc2[0]);
    acc2[1] = MFMA16(P.s, cat4(t2, t3), acc2[1]);
    acc2[2] = MFMA16(P.s, cat4(t4, t5), acc2[2]);
    acc2[3] = MFMA16(P.s, cat4(t6, t7), acc2[3]);
    acc2[4] = MFMA16(P.s, vb4, acc2[4]);

    // ---- write-late: next-tile ks conversion + fourier + hk, and v tile ----
    if (it < 15 && tid < 512) {
      float part = (kvn[0]*kvn[0] + kvn[1]*kvn[1] + kvn[2]*kvn[2] + kvn[3]*kvn[3]) * NORM2;
      s16x4 o;
#pragma unroll
      for (int i = 0; i < 4; ++i) o[i] = (short)f2bf(kvn[i]);
      *reinterpret_cast<s16x4*>(&sbuf[nxt][row * 256 + ((8 * seg) ^ s4)]) = o;
      if (seg < 8) {
        float ph = svn * wv;
        float e = issin ? sinf(ph) : cosf(ph);
        part += e * e;
        *reinterpret_cast<unsigned short*>(&sbuf[nxt][row * 256 + ((128 + 2 * seg) ^ s4)]) = f2bf(e);
      }
#pragma unroll
      for (int m = 1; m < 16; m <<= 1) part += __shfl_xor(part, m, 64);
      if (seg == 0) hk_sh[nxt][row] = 0.5f * part + LN16;
      uint2 vp = make_uint2(pk2(vvn[0], vvn[1]), pk2(vvn[2], vvn[3]));
      *reinterpret_cast<uint2*>(&sbuf[nxt][vwo]) = vp;
    }
    __syncthreads();
  }

#pragma unroll
  for (int ne = 0; ne < 5; ++ne)
#pragma unroll
    for (int r = 0; r < 4; ++r) {
      int m = 16 * w + 4 * l4 + r;
      parts[(((size_t)split * 32 + bh) * MM + m) * EE + l15 + 16 * ne] = acc2[ne][r];
    }
}

// ---------------------------------------------------------------------------
// reduce 8 splits -> b1F fragment-major [bh][ks(8)][ne(5)][lane][8] bf16.
// grid (32 bh, 8 mc): each block owns 32 m-rows = exactly one ks slot.
// ---------------------------------------------------------------------------
__global__ __launch_bounds__(256) void reduce_t(const float* __restrict__ parts,
                                                unsigned short* __restrict__ b1F) {
  int bh = blockIdx.x;   // 32
  int mc = blockIdx.y;   // 8 (32 m each) == ks slot
  __shared__ float s[32 * 80];
  size_t base = ((size_t)bh * MM + mc * 32) * EE;
  for (int o = threadIdx.x; o < 32 * 80; o += 256) {
    float sum = 0.f;
#pragma unroll
    for (int sp = 0; sp < NSPLIT; ++sp)
      sum += parts[(size_t)sp * 32 * MM * EE + base + o];
    s[o] = sum;
  }
  __syncthreads();
  int t = threadIdx.x, l = t & 63;
  int l15 = l & 15, l4 = l >> 4;
  for (int ne = t >> 6; ne < 5; ne += 4) {
    s16x8 o;
#pragma unroll
    for (int j = 0; j < 8; ++j) {
      int ml = 16 * (j >> 2) + 4 * l4 + (j & 3);
      o[j] = (short)f2bf(s[ml * 80 + l15 + 16 * ne]);
    }
    *reinterpret_cast<s16x8*>(
        b1F + (((size_t)bh * 8 + mc) * 5 + ne) * 64 * 8 + (size_t)l * 8) = o;
  }
}

// ---------------------------------------------------------------------------
// F2: fused {qs->frag + fourier + hq} + phi_q GEMM + exp + output GEMM.
// 1024 threads (16 waves x 32 q), grid (32 bh, 8 qc). R12 structure:
// coalesced projF + b1F staging from workspace, one barrier, pure-LDS loop.
// ---------------------------------------------------------------------------
__global__ __launch_bounds__(1024, 1) void f2_k(
    const float* __restrict__ qs, const float* __restrict__ qs_s,
    const float* __restrict__ W, const float* __restrict__ a,
    const unsigned short* __restrict__ projF,
    const unsigned short* __restrict__ b1F, float* __restrict__ out) {
  __shared__ unsigned short pf_lds[24576];   // 48 KB
  __shared__ unsigned short b1_lds[20480];   // 40 KB

  int bh = blockIdx.x, qc = blockIdx.y;
  int b = bh >> 3, h = bh & 7;
  int tid = threadIdx.x;
  int w = tid >> 6, l = tid & 63;
  int l15 = l & 15, l4 = l >> 4;
  int qb = qc * 512 + w * 32;
  const unsigned short* b1b = b1F + (size_t)bh * 8 * 5 * 64 * 8;
  float ah = a[h];

  {
    const u32x4* g1 = reinterpret_cast<const u32x4*>(projF);
    u32x4* s1 = reinterpret_cast<u32x4*>(pf_lds);
#pragma unroll
    for (int i = 0; i < 3; ++i) s1[i * 1024 + tid] = g1[i * 1024 + tid];
    const u32x4* g2 = reinterpret_cast<const u32x4*>(b1b);
    u32x4* s2 = reinterpret_cast<u32x4*>(b1_lds);
    s2[tid] = g2[tid];
    s2[1024 + tid] = g2[1024 + tid];
    if (tid < 512) s2[2048 + tid] = g2[2048 + tid];
  }

  s16x8 xq[2][3];
#pragma unroll
  for (int qt = 0; qt < 2; ++qt) {
    int qrow = qb + 16 * qt + l15;
    const float* qr = qs + ((size_t)(b * LLEN + qrow) * HH + h) * 64;
    float part = 0.f;
#pragma unroll
    for (int xs = 0; xs < 2; ++xs) {
      f32x4 u0 = *reinterpret_cast<const f32x4*>(qr + 32 * xs + 8 * l4);
      f32x4 u1 = *reinterpret_cast<const f32x4*>(qr + 32 * xs + 8 * l4 + 4);
      s16x8 fr;
#pragma unroll
      for (int i = 0; i < 4; ++i) {
        part += u0[i] * u0[i] + u1[i] * u1[i];
        fr[i] = (short)f2bf(u0[i]);
        fr[4 + i] = (short)f2bf(u1[i]);
      }
      xq[qt][xs] = fr;
    }
    part *= NORM2;
    s16x8 fx = {};
    if (l4 == 0) {
      float sv = qs_s[(size_t)b * LLEN + qrow] * TWO_PI_F;
#pragma unroll
      for (int j = 0; j < 8; ++j) {
        int dim = 8 * h + j;
        float ph = sv * W[dim & 31];
        float e = (dim < 32) ? sinf(ph) : cosf(ph);
        e *= ah;
        part += e * e;
        fx[j] = (short)f2bf(e);
      }
    }
    part += __shfl_xor(part, 16, 64);
    part += __shfl_xor(part, 32, 64);
    if (l4 == 1) fx[0] = (short)f2bf(0.5f * part + LN16);
    xq[qt][2] = fx;
  }
  __syncthreads();

  f32x4 acc3[2][5] = {};
#pragma unroll
  for (int ks = 0; ks < 8; ++ks) {
    f32x4 a0 = {}, b0 = {}, a1 = {}, b1 = {};
    __builtin_amdgcn_s_setprio(1);
#pragma unroll
    for (int xs = 0; xs < 3; ++xs) {
      s16x8 p0 = *reinterpret_cast<const s16x8*>(pf_lds + (((2 * ks) * 3 + xs) * 64 + l) * 8);
      s16x8 p1 = *reinterpret_cast<const s16x8*>(pf_lds + (((2 * ks + 1) * 3 + xs) * 64 + l) * 8);
      a0 = MFMA16(p0, xq[0][xs], a0);
      b0 = MFMA16(p1, xq[0][xs], b0);
      a1 = MFMA16(p0, xq[1][xs], a1);
      b1 = MFMA16(p1, xq[1][xs], b1);
    }
    __builtin_amdgcn_s_setprio(0);
    union { unsigned int u[4]; s16x8 s; } Pa, Pb;
    Pa.u[0] = pk2(__expf(a0[0]), __expf(a0[1]));
    Pa.u[1] = pk2(__expf(a0[2]), __expf(a0[3]));
    Pa.u[2] = pk2(__expf(b0[0]), __expf(b0[1]));
    Pa.u[3] = pk2(__expf(b0[2]), __expf(b0[3]));
    Pb.u[0] = pk2(__expf(a1[0]), __expf(a1[1]));
    Pb.u[1] = pk2(__expf(a1[2]), __expf(a1[3]));
    Pb.u[2] = pk2(__expf(b1[0]), __expf(b1[1]));
    Pb.u[3] = pk2(__expf(b1[2]), __expf(b1[3]));
    __builtin_amdgcn_s_setprio(1);
#pragma unroll
    for (int ne = 0; ne < 5; ++ne) {
      s16x8 vb = *reinterpret_cast<const s16x8*>(b1_lds + ((ks * 5 + ne) * 64 + l) * 8);
      acc3[0][ne] = MFMA16(Pa.s, vb, acc3[0][ne]);
      acc3[1][ne] = MFMA16(Pb.s, vb, acc3[1][ne]);
    }
    __builtin_amdgcn_s_setprio(0);
  }
#pragma unroll
  for (int qt = 0; qt < 2; ++qt) {
    float inv[4];
#pragma unroll
    for (int r = 0; r < 4; ++r) {
      float den = __shfl(acc3[qt][4][r], 16 * l4, 64);
      den = den < EPSV ? EPSV : den;
      inv[r] = 1.0f / den;
    }
#pragma unroll
    for (int ne = 0; ne < 4; ++ne)
#pragma unroll
      for (int r = 0; r < 4; ++r)
        out[((size_t)(b * LLEN + qb + 16 * qt + 4 * l4 + r) * HH + h) * 64 + l15 + 16 * ne] =
            acc3[qt][ne][r] * inv[r];
  }
}

// ---------------------------------------------------------------------------
extern "C" void kernel_launch(void* const* d_in, const int* in_sizes, int n_in,
                              void* d_out, int out_size, void* d_ws, size_t ws_size,
                              hipStream_t stream) {
  const float* qs   = (const float*)d_in[0];
  const float* ks   = (const float*)d_in[1];
  const float* vs   = (const float*)d_in[2];
  const float* qs_s = (const float*)d_in[3];
  const float* ks_s = (const float*)d_in[4];
  const float* W    = (const float*)d_in[5];
  const float* proj = (const float*)d_in[6];
  const float* a    = (const float*)d_in[7];
  float* out = (float*)d_out;

  char* ws = (char*)d_ws;
  unsigned short* projF = (unsigned short*)(ws + OFF_PROJF);
  float*          parts = (float*)(ws + OFF_PARTS);
  unsigned short* b1F   = (unsigned short*)(ws + OFF_B1F);

  prep_projF<<<1, 256, 0, stream>>>(proj, projF);
  f1_k<<<dim3(32, NSPLIT), 1024, 0, stream>>>(ks, ks_s, vs, W, projF, parts);
  reduce_t<<<dim3(32, 8), 256, 0, stream>>>(parts, b1F);
  f2_k<<<dim3(32, 8), 1024, 0, stream>>>(qs, qs_s, W, a, projF, b1F, out);
}

// Round 15
// 73.676 us; speedup vs baseline: 1.0684x; 1.0684x over previous
//
#include <hip/hip_runtime.h>
#include <hip/hip_bf16.h>
#include <math.h>

// Problem dims (fixed by setup_inputs)
#define BB 4
#define LLEN 4096
#define HH 8
#define MM 256
#define KX 96
#define EE 80          // padded c-dim: 64 v + 1 ones + 15 zero
#define NTOK 16384
#define NORM 0.35355339059327373f   // 64^-0.25 (folded into projF cols 0..63)
#define NORM2 0.125f                // NORM^2
#define LN16 2.7725887222397811f    // ln(sqrt(256)) folded into h
#define EPSV 1e-6f
#define TWO_PI_F 6.283185307179586f
#define NSPLIT 8

typedef __attribute__((ext_vector_type(8))) short s16x8;   // 8 bf16 (4 VGPRs)
typedef __attribute__((ext_vector_type(4))) short s16x4;   // 4 bf16 (2 VGPRs)
typedef __attribute__((ext_vector_type(4))) float f32x4;
typedef __attribute__((ext_vector_type(4))) unsigned int u32x4;

#define MFMA16(A,B,C) __builtin_amdgcn_mfma_f32_16x16x32_bf16(A,B,C,0,0,0)

static __device__ __forceinline__ unsigned short f2bf(float f) {
  union { float f; unsigned int u; } v; v.f = f;
  unsigned int r = v.u + 0x7FFFu + ((v.u >> 16) & 1u);   // RNE
  return (unsigned short)(r >> 16);
}
static __device__ __forceinline__ unsigned int pk2(float lo, float hi) {
  __hip_bfloat162 h = __float22bfloat162_rn(make_float2(lo, hi));
  union { __hip_bfloat162 h; unsigned int u; } c; c.h = h;
  return c.u;
}
static __device__ __forceinline__ s16x8 cat4(s16x4 a, s16x4 b) {
  s16x8 r;
  r[0]=a[0]; r[1]=a[1]; r[2]=a[2]; r[3]=a[3];
  r[4]=b[0]; r[5]=b[1]; r[6]=b[2]; r[7]=b[3];
  return r;
}

// ---- workspace byte offsets ----
#define OFF_PROJF 0u
#define OFF_PARTS 524288u
#define OFF_B1F   (OFF_PARTS + 20971520u)   // NSPLIT=8 parts

// ---------------------------------------------------------------------------
// projF fragment-major: chunk c = mt*3+xs, lane l, j:
//   projLogical[(l&15)+16mt][32xs+8(l>>4)+j]; cols: 0..63 proj*NORM,
//   64..71 proj, 72 = -1 (hq fold), 73..95 = 0.
// ---------------------------------------------------------------------------
__global__ __launch_bounds__(256) void prep_projF(const float* __restrict__ proj,
                                                  unsigned short* __restrict__ projF) {
  int t = threadIdx.x;
  int l = t & 63, grp = t >> 6;
  int l15 = l & 15, l4 = l >> 4;
  for (int c = grp; c < 48; c += 4) {
    int mt = c / 3, xs = c % 3;
    int m = l15 + 16 * mt;
    s16x8 o;
#pragma unroll
    for (int j = 0; j < 8; ++j) {
      int d = 32 * xs + 8 * l4 + j;
      unsigned short u;
      if (d < 64)       u = f2bf(proj[m * 72 + d] * NORM);
      else if (d < 72)  u = f2bf(proj[m * 72 + d]);
      else if (d == 72) u = 0xBF80;  // bf16(-1)
      else              u = 0;
      o[j] = (short)u;
    }
    *reinterpret_cast<s16x8*>(projF + ((size_t)c * 64 + l) * 8) = o;
  }
}

// ---------------------------------------------------------------------------
// F1: fused {ks->bf16 + fourier + hk} + phi_k GEMM + exp + buf1 GEMM with
// V via ds_read_b64_tr_b16 (slot model: col = (A>>3)&15, A = base+128l4+8l15).
// 1024 threads (16 waves, 1 m-tile each), grid (32 bh, 8 splits).
// ---------------------------------------------------------------------------
__global__ __launch_bounds__(1024, 1) void f1_k(
    const float* __restrict__ ks, const float* __restrict__ ks_s,
    const float* __restrict__ vs, const float* __restrict__ W,
    const unsigned short* __restrict__ projF,
    float* __restrict__ parts) {
  __shared__ unsigned short pf_lds[24576];             // 48 KB
  __shared__ alignas(16) unsigned char sbuf[2][12288]; // [0..8191]=ks tile, [8192..]=v tile
  __shared__ alignas(16) float hk_sh[2][32];

  int bh = blockIdx.x, split = blockIdx.y;
  int b = bh >> 3, h = bh & 7;
  int tid = threadIdx.x;
  int w = tid >> 6, l = tid & 63;
  int l15 = l & 15, l4 = l >> 4;
  int kbase = split * 512;
  int row = tid >> 4, seg = tid & 15;   // staging roles, tid<512
  int s4 = (row & 7) << 4;

  const float* ksb = ks + ((size_t)(b * LLEN + kbase) * HH + h) * 64;  // stride 512 f32/key
  const float* vsb = vs + ((size_t)(b * LLEN + kbase) * HH + h) * 64;
  const float* kss = ks_s + (size_t)b * LLEN + kbase;

  float wv = 0.f; bool issin = false;
  if (seg < 8) { int dim = 8 * h + seg; wv = W[dim & 31] * TWO_PI_F; issin = dim < 32; }

  // v-tile write slot: [ne=seg>>2][k=row][4(seg&3)..+3]
  int vwo = 8192 + (seg >> 2) * 1024 + row * 32 + (seg & 3) * 8;

  // ---- prologue: zero upper 128B of ks rows (both bufs) + stage projF ----
  if (tid < 512) {
    int bi = tid >> 8, rem = tid & 255;
    u32x4 z = {};
    *reinterpret_cast<u32x4*>(&sbuf[bi][(rem >> 3) * 256 + 128 + (rem & 7) * 16]) = z;
  }
  {
    const u32x4* g1 = reinterpret_cast<const u32x4*>(projF);
    u32x4* s1 = reinterpret_cast<u32x4*>(pf_lds);
#pragma unroll
    for (int i = 0; i < 3; ++i) s1[i * 1024 + tid] = g1[i * 1024 + tid];
  }
  __syncthreads();
  // ---- stage tile 0: ks (+fourier+hk) and v ----
  if (tid < 512) {
    f32x4 kv = *reinterpret_cast<const f32x4*>(ksb + (size_t)row * 512 + 4 * seg);
    float part = (kv[0]*kv[0] + kv[1]*kv[1] + kv[2]*kv[2] + kv[3]*kv[3]) * NORM2;
    s16x4 o;
#pragma unroll
    for (int i = 0; i < 4; ++i) o[i] = (short)f2bf(kv[i]);
    *reinterpret_cast<s16x4*>(&sbuf[0][row * 256 + ((8 * seg) ^ s4)]) = o;
    if (seg < 8) {
      float ph = kss[row] * wv;
      float e = issin ? sinf(ph) : cosf(ph);
      part += e * e;
      *reinterpret_cast<unsigned short*>(&sbuf[0][row * 256 + ((128 + 2 * seg) ^ s4)]) = f2bf(e);
    }
#pragma unroll
    for (int m = 1; m < 16; m <<= 1) part += __shfl_xor(part, m, 64);
    if (seg == 0) hk_sh[0][row] = 0.5f * part + LN16;
    f32x4 vv = *reinterpret_cast<const f32x4*>(vsb + (size_t)row * 512 + 4 * seg);
    uint2 vp = make_uint2(pk2(vv[0], vv[1]), pk2(vv[2], vv[3]));
    *reinterpret_cast<uint2*>(&sbuf[0][vwo]) = vp;
  }
  __syncthreads();

  // constant ne=4 B-frag: c[k][e=64+l15] = (l15==0) ? 1 : 0
  s16x8 vb4 = {};
  if (l15 == 0) {
#pragma unroll
    for (int j = 0; j < 8; ++j) vb4[j] = (short)0x3F80;
  }

  f32x4 acc2[5] = {};

  for (int it = 0; it < 16; ++it) {
    int cur = it & 1, nxt = cur ^ 1;
    // issue-early: next-tile global loads
    f32x4 kvn, vvn; float svn = 0.f;
    if (it < 15 && tid < 512) {
      kvn = *reinterpret_cast<const f32x4*>(ksb + (size_t)(32 * (it + 1) + row) * 512 + 4 * seg);
      vvn = *reinterpret_cast<const f32x4*>(vsb + (size_t)(32 * (it + 1) + row) * 512 + 4 * seg);
      if (seg < 8) svn = kss[32 * (it + 1) + row];
    }

    // ---- GEMM1: P = Xk . projF^T (wave's single m-tile) ----
    f32x4 acc1_0 = {}, acc1_1 = {};
#pragma unroll
    for (int xs = 0; xs < 3; ++xs) {
      int co = (64 * xs + 16 * l4) ^ ((l15 & 7) << 4);
      s16x8 ak0 = *reinterpret_cast<const s16x8*>(&sbuf[cur][l15 * 256 + co]);
      s16x8 ak1 = *reinterpret_cast<const s16x8*>(&sbuf[cur][(16 + l15) * 256 + co]);
      s16x8 pf = *reinterpret_cast<const s16x8*>(pf_lds + ((w * 3 + xs) * 64 + l) * 8);
      acc1_0 = MFMA16(ak0, pf, acc1_0);
      acc1_1 = MFMA16(ak1, pf, acc1_1);
    }
    // ---- exp -> bf16 A-frag ----
    f32x4 hk0 = *reinterpret_cast<const f32x4*>(&hk_sh[cur][4 * l4]);
    f32x4 hk1 = *reinterpret_cast<const f32x4*>(&hk_sh[cur][16 + 4 * l4]);
    union { unsigned int u[4]; s16x8 s; } P;
    P.u[0] = pk2(__expf(acc1_0[0] - hk0[0]), __expf(acc1_0[1] - hk0[1]));
    P.u[1] = pk2(__expf(acc1_0[2] - hk0[2]), __expf(acc1_0[3] - hk0[3]));
    P.u[2] = pk2(__expf(acc1_1[0] - hk1[0]), __expf(acc1_1[1] - hk1[1]));
    P.u[3] = pk2(__expf(acc1_1[2] - hk1[2]), __expf(acc1_1[3] - hk1[3]));

    // ---- GEMM2 B-frags via HW transpose-read from v tile ----
    unsigned int va = (unsigned int)(size_t)(&sbuf[cur][8192]) + 8 * l15 + 128 * l4;
    s16x4 t0, t1, t2, t3, t4, t5, t6, t7;
    asm volatile(
        "ds_read_b64_tr_b16 %0, %8 offset:0\n\t"
        "ds_read_b64_tr_b16 %1, %8 offset:512\n\t"
        "ds_read_b64_tr_b16 %2, %8 offset:1024\n\t"
        "ds_read_b64_tr_b16 %3, %8 offset:1536\n\t"
        "ds_read_b64_tr_b16 %4, %8 offset:2048\n\t"
        "ds_read_b64_tr_b16 %5, %8 offset:2560\n\t"
        "ds_read_b64_tr_b16 %6, %8 offset:3072\n\t"
        "ds_read_b64_tr_b16 %7, %8 offset:3584"
        : "=&v"(t0), "=&v"(t1), "=&v"(t2), "=&v"(t3),
          "=&v"(t4), "=&v"(t5), "=&v"(t6), "=&v"(t7)
        : "v"(va)
        : "memory");
    asm volatile("s_waitcnt lgkmcnt(0)" ::: "memory");
    __builtin_amdgcn_sched_barrier(0);

    acc2[0] = MFMA16(P.s, cat4(t0, t1), acc2[0]);
    acc2[1] = MFMA16(P.s, cat4(t2, t3), acc2[1]);
    acc2[2] = MFMA16(P.s, cat4(t4, t5), acc2[2]);
    acc2[3] = MFMA16(P.s, cat4(t6, t7), acc2[3]);
    acc2[4] = MFMA16(P.s, vb4, acc2[4]);

    // ---- write-late: next-tile ks conversion + fourier + hk, and v tile ----
    if (it < 15 && tid < 512) {
      float part = (kvn[0]*kvn[0] + kvn[1]*kvn[1] + kvn[2]*kvn[2] + kvn[3]*kvn[3]) * NORM2;
      s16x4 o;
#pragma unroll
      for (int i = 0; i < 4; ++i) o[i] = (short)f2bf(kvn[i]);
      *reinterpret_cast<s16x4*>(&sbuf[nxt][row * 256 + ((8 * seg) ^ s4)]) = o;
      if (seg < 8) {
        float ph = svn * wv;
        float e = issin ? sinf(ph) : cosf(ph);
        part += e * e;
        *reinterpret_cast<unsigned short*>(&sbuf[nxt][row * 256 + ((128 + 2 * seg) ^ s4)]) = f2bf(e);
      }
#pragma unroll
      for (int m = 1; m < 16; m <<= 1) part += __shfl_xor(part, m, 64);
      if (seg == 0) hk_sh[nxt][row] = 0.5f * part + LN16;
      uint2 vp = make_uint2(pk2(vvn[0], vvn[1]), pk2(vvn[2], vvn[3]));
      *reinterpret_cast<uint2*>(&sbuf[nxt][vwo]) = vp;
    }
    __syncthreads();
  }

#pragma unroll
  for (int ne = 0; ne < 5; ++ne)
#pragma unroll
    for (int r = 0; r < 4; ++r) {
      int m = 16 * w + 4 * l4 + r;
      parts[(((size_t)split * 32 + bh) * MM + m) * EE + l15 + 16 * ne] = acc2[ne][r];
    }
}

// ---------------------------------------------------------------------------
// reduce 8 splits -> b1F fragment-major [bh][ks(8)][ne(5)][lane][8] bf16
// (R12 version: grid (32,4), 64 m-rows per block)
// ---------------------------------------------------------------------------
__global__ __launch_bounds__(256) void reduce_t(const float* __restrict__ parts,
                                                unsigned short* __restrict__ b1F) {
  int bh = blockIdx.x;   // 32
  int mc = blockIdx.y;   // 4 (64 m each)
  __shared__ float s[64 * 80];
  size_t base = ((size_t)bh * MM + mc * 64) * EE;
  for (int o = threadIdx.x; o < 64 * 80; o += 256) {
    float sum = 0.f;
#pragma unroll
    for (int sp = 0; sp < NSPLIT; ++sp)
      sum += parts[(size_t)sp * 32 * MM * EE + base + o];
    s[o] = sum;
  }
  __syncthreads();
  int t = threadIdx.x, l = t & 63, kl = (t >> 6) & 1, rep = t >> 7;
  int l15 = l & 15, l4 = l >> 4;
  int nelo = rep ? 3 : 0, nehi = rep ? 5 : 3;
  for (int ne = nelo; ne < nehi; ++ne) {
    s16x8 o;
#pragma unroll
    for (int j = 0; j < 8; ++j) {
      int ml = 32 * kl + 16 * (j >> 2) + 4 * l4 + (j & 3);
      o[j] = (short)f2bf(s[ml * 80 + l15 + 16 * ne]);
    }
    int ks = mc * 2 + kl;
    *reinterpret_cast<s16x8*>(
        b1F + (((size_t)bh * 8 + ks) * 5 + ne) * 64 * 8 + (size_t)l * 8) = o;
  }
}

// ---------------------------------------------------------------------------
// F2: fused {qs->frag + fourier + hq} + phi_q GEMM + exp + output GEMM.
// 1024 threads (16 waves x 32 q), grid (32 bh, 8 qc). Coalesced projF + b1F
// staging from workspace, one barrier, pure-LDS loop. (R12 version)
// ---------------------------------------------------------------------------
__global__ __launch_bounds__(1024, 1) void f2_k(
    const float* __restrict__ qs, const float* __restrict__ qs_s,
    const float* __restrict__ W, const float* __restrict__ a,
    const unsigned short* __restrict__ projF,
    const unsigned short* __restrict__ b1F, float* __restrict__ out) {
  __shared__ unsigned short pf_lds[24576];   // 48 KB
  __shared__ unsigned short b1_lds[20480];   // 40 KB

  int bh = blockIdx.x, qc = blockIdx.y;
  int b = bh >> 3, h = bh & 7;
  int tid = threadIdx.x;
  int w = tid >> 6, l = tid & 63;
  int l15 = l & 15, l4 = l >> 4;
  int qb = qc * 512 + w * 32;
  const unsigned short* b1b = b1F + (size_t)bh * 8 * 5 * 64 * 8;
  float ah = a[h];

  {
    const u32x4* g1 = reinterpret_cast<const u32x4*>(projF);
    u32x4* s1 = reinterpret_cast<u32x4*>(pf_lds);
#pragma unroll
    for (int i = 0; i < 3; ++i) s1[i * 1024 + tid] = g1[i * 1024 + tid];
    const u32x4* g2 = reinterpret_cast<const u32x4*>(b1b);
    u32x4* s2 = reinterpret_cast<u32x4*>(b1_lds);
    s2[tid] = g2[tid];
    s2[1024 + tid] = g2[1024 + tid];
    if (tid < 512) s2[2048 + tid] = g2[2048 + tid];
  }

  s16x8 xq[2][3];
#pragma unroll
  for (int qt = 0; qt < 2; ++qt) {
    int qrow = qb + 16 * qt + l15;
    const float* qr = qs + ((size_t)(b * LLEN + qrow) * HH + h) * 64;
    float part = 0.f;
#pragma unroll
    for (int xs = 0; xs < 2; ++xs) {
      f32x4 u0 = *reinterpret_cast<const f32x4*>(qr + 32 * xs + 8 * l4);
      f32x4 u1 = *reinterpret_cast<const f32x4*>(qr + 32 * xs + 8 * l4 + 4);
      s16x8 fr;
#pragma unroll
      for (int i = 0; i < 4; ++i) {
        part += u0[i] * u0[i] + u1[i] * u1[i];
        fr[i] = (short)f2bf(u0[i]);
        fr[4 + i] = (short)f2bf(u1[i]);
      }
      xq[qt][xs] = fr;
    }
    part *= NORM2;
    s16x8 fx = {};
    if (l4 == 0) {
      float sv = qs_s[(size_t)b * LLEN + qrow] * TWO_PI_F;
#pragma unroll
      for (int j = 0; j < 8; ++j) {
        int dim = 8 * h + j;
        float ph = sv * W[dim & 31];
        float e = (dim < 32) ? sinf(ph) : cosf(ph);
        e *= ah;
        part += e * e;
        fx[j] = (short)f2bf(e);
      }
    }
    part += __shfl_xor(part, 16, 64);
    part += __shfl_xor(part, 32, 64);
    if (l4 == 1) fx[0] = (short)f2bf(0.5f * part + LN16);
    xq[qt][2] = fx;
  }
  __syncthreads();

  f32x4 acc3[2][5] = {};
#pragma unroll
  for (int ks = 0; ks < 8; ++ks) {
    f32x4 a0 = {}, b0 = {}, a1 = {}, b1 = {};
    __builtin_amdgcn_s_setprio(1);
#pragma unroll
    for (int xs = 0; xs < 3; ++xs) {
      s16x8 p0 = *reinterpret_cast<const s16x8*>(pf_lds + (((2 * ks) * 3 + xs) * 64 + l) * 8);
      s16x8 p1 = *reinterpret_cast<const s16x8*>(pf_lds + (((2 * ks + 1) * 3 + xs) * 64 + l) * 8);
      a0 = MFMA16(p0, xq[0][xs], a0);
      b0 = MFMA16(p1, xq[0][xs], b0);
      a1 = MFMA16(p0, xq[1][xs], a1);
      b1 = MFMA16(p1, xq[1][xs], b1);
    }
    __builtin_amdgcn_s_setprio(0);
    union { unsigned int u[4]; s16x8 s; } Pa, Pb;
    Pa.u[0] = pk2(__expf(a0[0]), __expf(a0[1]));
    Pa.u[1] = pk2(__expf(a0[2]), __expf(a0[3]));
    Pa.u[2] = pk2(__expf(b0[0]), __expf(b0[1]));
    Pa.u[3] = pk2(__expf(b0[2]), __expf(b0[3]));
    Pb.u[0] = pk2(__expf(a1[0]), __expf(a1[1]));
    Pb.u[1] = pk2(__expf(a1[2]), __expf(a1[3]));
    Pb.u[2] = pk2(__expf(b1[0]), __expf(b1[1]));
    Pb.u[3] = pk2(__expf(b1[2]), __expf(b1[3]));
    __builtin_amdgcn_s_setprio(1);
#pragma unroll
    for (int ne = 0; ne < 5; ++ne) {
      s16x8 vb = *reinterpret_cast<const s16x8*>(b1_lds + ((ks * 5 + ne) * 64 + l) * 8);
      acc3[0][ne] = MFMA16(Pa.s, vb, acc3[0][ne]);
      acc3[1][ne] = MFMA16(Pb.s, vb, acc3[1][ne]);
    }
    __builtin_amdgcn_s_setprio(0);
  }
#pragma unroll
  for (int qt = 0; qt < 2; ++qt) {
    float inv[4];
#pragma unroll
    for (int r = 0; r < 4; ++r) {
      float den = __shfl(acc3[qt][4][r], 16 * l4, 64);
      den = den < EPSV ? EPSV : den;
      inv[r] = 1.0f / den;
    }
#pragma unroll
    for (int ne = 0; ne < 4; ++ne)
#pragma unroll
      for (int r = 0; r < 4; ++r)
        out[((size_t)(b * LLEN + qb + 16 * qt + 4 * l4 + r) * HH + h) * 64 + l15 + 16 * ne] =
            acc3[qt][ne][r] * inv[r];
  }
}

// ---------------------------------------------------------------------------
extern "C" void kernel_launch(void* const* d_in, const int* in_sizes, int n_in,
                              void* d_out, int out_size, void* d_ws, size_t ws_size,
                              hipStream_t stream) {
  const float* qs   = (const float*)d_in[0];
  const float* ks   = (const float*)d_in[1];
  const float* vs   = (const float*)d_in[2];
  const float* qs_s = (const float*)d_in[3];
  const float* ks_s = (const float*)d_in[4];
  const float* W    = (const float*)d_in[5];
  const float* proj = (const float*)d_in[6];
  const float* a    = (const float*)d_in[7];
  float* out = (float*)d_out;

  char* ws = (char*)d_ws;
  unsigned short* projF = (unsigned short*)(ws + OFF_PROJF);
  float*          parts = (float*)(ws + OFF_PARTS);
  unsigned short* b1F   = (unsigned short*)(ws + OFF_B1F);

  prep_projF<<<1, 256, 0, stream>>>(proj, projF);
  f1_k<<<dim3(32, NSPLIT), 1024, 0, stream>>>(ks, ks_s, vs, W, projF, parts);
  reduce_t<<<dim3(32, 4), 256, 0, stream>>>(parts, b1F);
  f2_k<<<dim3(32, 8), 1024, 0, stream>>>(qs, qs_s, W, a, projF, b1F, out);
}

// Round 16
// 73.423 us; speedup vs baseline: 1.0720x; 1.0034x over previous
//
#include <hip/hip_runtime.h>
#include <hip/hip_bf16.h>
#include <math.h>

// Problem dims (fixed by setup_inputs)
#define BB 4
#define LLEN 4096
#define HH 8
#define MM 256
#define KX 96
#define EE 80          // padded c-dim: 64 v + 1 ones + 15 zero
#define NTOK 16384
#define NORM 0.35355339059327373f   // 64^-0.25 (folded into projF cols 0..63)
#define NORM2 0.125f                // NORM^2
#define LN16 2.7725887222397811f    // ln(sqrt(256)) folded into h
#define EPSV 1e-6f
#define TWO_PI_F 6.283185307179586f
#define NSPLIT 8

typedef __attribute__((ext_vector_type(8))) short s16x8;   // 8 bf16 (4 VGPRs)
typedef __attribute__((ext_vector_type(4))) short s16x4;   // 4 bf16 (2 VGPRs)
typedef __attribute__((ext_vector_type(4))) float f32x4;
typedef __attribute__((ext_vector_type(4))) unsigned int u32x4;

#define MFMA16(A,B,C) __builtin_amdgcn_mfma_f32_16x16x32_bf16(A,B,C,0,0,0)

static __device__ __forceinline__ unsigned short f2bf(float f) {
  union { float f; unsigned int u; } v; v.f = f;
  unsigned int r = v.u + 0x7FFFu + ((v.u >> 16) & 1u);   // RNE
  return (unsigned short)(r >> 16);
}
static __device__ __forceinline__ float bf2f(unsigned short u) {
  union { unsigned int u; float f; } v; v.u = (unsigned int)u << 16;
  return v.f;
}
static __device__ __forceinline__ unsigned int pk2(float lo, float hi) {
  __hip_bfloat162 h = __float22bfloat162_rn(make_float2(lo, hi));
  union { __hip_bfloat162 h; unsigned int u; } c; c.h = h;
  return c.u;
}
static __device__ __forceinline__ s16x8 cat4(s16x4 a, s16x4 b) {
  s16x8 r;
  r[0]=a[0]; r[1]=a[1]; r[2]=a[2]; r[3]=a[3];
  r[4]=b[0]; r[5]=b[1]; r[6]=b[2]; r[7]=b[3];
  return r;
}

// ---- workspace byte offsets ----
#define OFF_PROJF 0u
#define OFF_PARTS 524288u
#define OFF_B1F   (OFF_PARTS + 10485760u)   // NSPLIT=8 bf16 parts

// ---------------------------------------------------------------------------
// projF fragment-major: chunk c = mt*3+xs, lane l, j:
//   projLogical[(l&15)+16mt][32xs+8(l>>4)+j]; cols: 0..63 proj*NORM,
//   64..71 proj, 72 = -1 (hq fold), 73..95 = 0.
// ---------------------------------------------------------------------------
__global__ __launch_bounds__(256) void prep_projF(const float* __restrict__ proj,
                                                  unsigned short* __restrict__ projF) {
  int t = threadIdx.x;
  int l = t & 63, grp = t >> 6;
  int l15 = l & 15, l4 = l >> 4;
  for (int c = grp; c < 48; c += 4) {
    int mt = c / 3, xs = c % 3;
    int m = l15 + 16 * mt;
    s16x8 o;
#pragma unroll
    for (int j = 0; j < 8; ++j) {
      int d = 32 * xs + 8 * l4 + j;
      unsigned short u;
      if (d < 64)       u = f2bf(proj[m * 72 + d] * NORM);
      else if (d < 72)  u = f2bf(proj[m * 72 + d]);
      else if (d == 72) u = 0xBF80;  // bf16(-1)
      else              u = 0;
      o[j] = (short)u;
    }
    *reinterpret_cast<s16x8*>(projF + ((size_t)c * 64 + l) * 8) = o;
  }
}

// ---------------------------------------------------------------------------
// F1: fused {ks->bf16 + fourier + hk} + phi_k GEMM + exp + buf1 GEMM with
// V via ds_read_b64_tr_b16 (slot model: col = (A>>3)&15, A = base+128l4+8l15).
// 1024 threads (16 waves, 1 m-tile each), grid (32 bh, 8 splits).
// parts written as bf16 (halves split-K spill traffic).
// ---------------------------------------------------------------------------
__global__ __launch_bounds__(1024, 1) void f1_k(
    const float* __restrict__ ks, const float* __restrict__ ks_s,
    const float* __restrict__ vs, const float* __restrict__ W,
    const unsigned short* __restrict__ projF,
    unsigned short* __restrict__ parts) {
  __shared__ unsigned short pf_lds[24576];             // 48 KB
  __shared__ alignas(16) unsigned char sbuf[2][12288]; // [0..8191]=ks tile, [8192..]=v tile
  __shared__ alignas(16) float hk_sh[2][32];

  int bh = blockIdx.x, split = blockIdx.y;
  int b = bh >> 3, h = bh & 7;
  int tid = threadIdx.x;
  int w = tid >> 6, l = tid & 63;
  int l15 = l & 15, l4 = l >> 4;
  int kbase = split * 512;
  int row = tid >> 4, seg = tid & 15;   // staging roles, tid<512
  int s4 = (row & 7) << 4;

  const float* ksb = ks + ((size_t)(b * LLEN + kbase) * HH + h) * 64;  // stride 512 f32/key
  const float* vsb = vs + ((size_t)(b * LLEN + kbase) * HH + h) * 64;
  const float* kss = ks_s + (size_t)b * LLEN + kbase;

  float wv = 0.f; bool issin = false;
  if (seg < 8) { int dim = 8 * h + seg; wv = W[dim & 31] * TWO_PI_F; issin = dim < 32; }

  // v-tile write slot: [ne=seg>>2][k=row][4(seg&3)..+3]
  int vwo = 8192 + (seg >> 2) * 1024 + row * 32 + (seg & 3) * 8;

  // ---- prologue: zero upper 128B of ks rows (both bufs) + stage projF ----
  if (tid < 512) {
    int bi = tid >> 8, rem = tid & 255;
    u32x4 z = {};
    *reinterpret_cast<u32x4*>(&sbuf[bi][(rem >> 3) * 256 + 128 + (rem & 7) * 16]) = z;
  }
  {
    const u32x4* g1 = reinterpret_cast<const u32x4*>(projF);
    u32x4* s1 = reinterpret_cast<u32x4*>(pf_lds);
#pragma unroll
    for (int i = 0; i < 3; ++i) s1[i * 1024 + tid] = g1[i * 1024 + tid];
  }
  __syncthreads();
  // ---- stage tile 0: ks (+fourier+hk) and v ----
  if (tid < 512) {
    f32x4 kv = *reinterpret_cast<const f32x4*>(ksb + (size_t)row * 512 + 4 * seg);
    float part = (kv[0]*kv[0] + kv[1]*kv[1] + kv[2]*kv[2] + kv[3]*kv[3]) * NORM2;
    s16x4 o;
#pragma unroll
    for (int i = 0; i < 4; ++i) o[i] = (short)f2bf(kv[i]);
    *reinterpret_cast<s16x4*>(&sbuf[0][row * 256 + ((8 * seg) ^ s4)]) = o;
    if (seg < 8) {
      float ph = kss[row] * wv;
      float e = issin ? sinf(ph) : cosf(ph);
      part += e * e;
      *reinterpret_cast<unsigned short*>(&sbuf[0][row * 256 + ((128 + 2 * seg) ^ s4)]) = f2bf(e);
    }
#pragma unroll
    for (int m = 1; m < 16; m <<= 1) part += __shfl_xor(part, m, 64);
    if (seg == 0) hk_sh[0][row] = 0.5f * part + LN16;
    f32x4 vv = *reinterpret_cast<const f32x4*>(vsb + (size_t)row * 512 + 4 * seg);
    uint2 vp = make_uint2(pk2(vv[0], vv[1]), pk2(vv[2], vv[3]));
    *reinterpret_cast<uint2*>(&sbuf[0][vwo]) = vp;
  }
  __syncthreads();

  // constant ne=4 B-frag: c[k][e=64+l15] = (l15==0) ? 1 : 0
  s16x8 vb4 = {};
  if (l15 == 0) {
#pragma unroll
    for (int j = 0; j < 8; ++j) vb4[j] = (short)0x3F80;
  }

  f32x4 acc2[5] = {};

  for (int it = 0; it < 16; ++it) {
    int cur = it & 1, nxt = cur ^ 1;
    // issue-early: next-tile global loads
    f32x4 kvn, vvn; float svn = 0.f;
    if (it < 15 && tid < 512) {
      kvn = *reinterpret_cast<const f32x4*>(ksb + (size_t)(32 * (it + 1) + row) * 512 + 4 * seg);
      vvn = *reinterpret_cast<const f32x4*>(vsb + (size_t)(32 * (it + 1) + row) * 512 + 4 * seg);
      if (seg < 8) svn = kss[32 * (it + 1) + row];
    }

    // ---- GEMM1: P = Xk . projF^T (wave's single m-tile) ----
    f32x4 acc1_0 = {}, acc1_1 = {};
#pragma unroll
    for (int xs = 0; xs < 3; ++xs) {
      int co = (64 * xs + 16 * l4) ^ ((l15 & 7) << 4);
      s16x8 ak0 = *reinterpret_cast<const s16x8*>(&sbuf[cur][l15 * 256 + co]);
      s16x8 ak1 = *reinterpret_cast<const s16x8*>(&sbuf[cur][(16 + l15) * 256 + co]);
      s16x8 pf = *reinterpret_cast<const s16x8*>(pf_lds + ((w * 3 + xs) * 64 + l) * 8);
      acc1_0 = MFMA16(ak0, pf, acc1_0);
      acc1_1 = MFMA16(ak1, pf, acc1_1);
    }
    // ---- exp -> bf16 A-frag ----
    f32x4 hk0 = *reinterpret_cast<const f32x4*>(&hk_sh[cur][4 * l4]);
    f32x4 hk1 = *reinterpret_cast<const f32x4*>(&hk_sh[cur][16 + 4 * l4]);
    union { unsigned int u[4]; s16x8 s; } P;
    P.u[0] = pk2(__expf(acc1_0[0] - hk0[0]), __expf(acc1_0[1] - hk0[1]));
    P.u[1] = pk2(__expf(acc1_0[2] - hk0[2]), __expf(acc1_0[3] - hk0[3]));
    P.u[2] = pk2(__expf(acc1_1[0] - hk1[0]), __expf(acc1_1[1] - hk1[1]));
    P.u[3] = pk2(__expf(acc1_1[2] - hk1[2]), __expf(acc1_1[3] - hk1[3]));

    // ---- GEMM2 B-frags via HW transpose-read from v tile ----
    unsigned int va = (unsigned int)(size_t)(&sbuf[cur][8192]) + 8 * l15 + 128 * l4;
    s16x4 t0, t1, t2, t3, t4, t5, t6, t7;
    asm volatile(
        "ds_read_b64_tr_b16 %0, %8 offset:0\n\t"
        "ds_read_b64_tr_b16 %1, %8 offset:512\n\t"
        "ds_read_b64_tr_b16 %2, %8 offset:1024\n\t"
        "ds_read_b64_tr_b16 %3, %8 offset:1536\n\t"
        "ds_read_b64_tr_b16 %4, %8 offset:2048\n\t"
        "ds_read_b64_tr_b16 %5, %8 offset:2560\n\t"
        "ds_read_b64_tr_b16 %6, %8 offset:3072\n\t"
        "ds_read_b64_tr_b16 %7, %8 offset:3584"
        : "=&v"(t0), "=&v"(t1), "=&v"(t2), "=&v"(t3),
          "=&v"(t4), "=&v"(t5), "=&v"(t6), "=&v"(t7)
        : "v"(va)
        : "memory");
    asm volatile("s_waitcnt lgkmcnt(0)" ::: "memory");
    __builtin_amdgcn_sched_barrier(0);

    acc2[0] = MFMA16(P.s, cat4(t0, t1), acc2[0]);
    acc2[1] = MFMA16(P.s, cat4(t2, t3), acc2[1]);
    acc2[2] = MFMA16(P.s, cat4(t4, t5), acc2[2]);
    acc2[3] = MFMA16(P.s, cat4(t6, t7), acc2[3]);
    acc2[4] = MFMA16(P.s, vb4, acc2[4]);

    // ---- write-late: next-tile ks conversion + fourier + hk, and v tile ----
    if (it < 15 && tid < 512) {
      float part = (kvn[0]*kvn[0] + kvn[1]*kvn[1] + kvn[2]*kvn[2] + kvn[3]*kvn[3]) * NORM2;
      s16x4 o;
#pragma unroll
      for (int i = 0; i < 4; ++i) o[i] = (short)f2bf(kvn[i]);
      *reinterpret_cast<s16x4*>(&sbuf[nxt][row * 256 + ((8 * seg) ^ s4)]) = o;
      if (seg < 8) {
        float ph = svn * wv;
        float e = issin ? sinf(ph) : cosf(ph);
        part += e * e;
        *reinterpret_cast<unsigned short*>(&sbuf[nxt][row * 256 + ((128 + 2 * seg) ^ s4)]) = f2bf(e);
      }
#pragma unroll
      for (int m = 1; m < 16; m <<= 1) part += __shfl_xor(part, m, 64);
      if (seg == 0) hk_sh[nxt][row] = 0.5f * part + LN16;
      uint2 vp = make_uint2(pk2(vvn[0], vvn[1]), pk2(vvn[2], vvn[3]));
      *reinterpret_cast<uint2*>(&sbuf[nxt][vwo]) = vp;
    }
    __syncthreads();
  }

#pragma unroll
  for (int ne = 0; ne < 5; ++ne)
#pragma unroll
    for (int r = 0; r < 4; ++r) {
      int m = 16 * w + 4 * l4 + r;
      parts[(((size_t)split * 32 + bh) * MM + m) * EE + l15 + 16 * ne] = f2bf(acc2[ne][r]);
    }
}

// ---------------------------------------------------------------------------
// reduce 8 bf16 splits -> b1F fragment-major [bh][ks(8)][ne(5)][lane][8] bf16
// (grid (32,4), 64 m-rows per block)
// ---------------------------------------------------------------------------
__global__ __launch_bounds__(256) void reduce_t(const unsigned short* __restrict__ parts,
                                                unsigned short* __restrict__ b1F) {
  int bh = blockIdx.x;   // 32
  int mc = blockIdx.y;   // 4 (64 m each)
  __shared__ float s[64 * 80];
  size_t base = ((size_t)bh * MM + mc * 64) * EE;
  for (int o = threadIdx.x; o < 64 * 80; o += 256) {
    float sum = 0.f;
#pragma unroll
    for (int sp = 0; sp < NSPLIT; ++sp)
      sum += bf2f(parts[(size_t)sp * 32 * MM * EE + base + o]);
    s[o] = sum;
  }
  __syncthreads();
  int t = threadIdx.x, l = t & 63, kl = (t >> 6) & 1, rep = t >> 7;
  int l15 = l & 15, l4 = l >> 4;
  int nelo = rep ? 3 : 0, nehi = rep ? 5 : 3;
  for (int ne = nelo; ne < nehi; ++ne) {
    s16x8 o;
#pragma unroll
    for (int j = 0; j < 8; ++j) {
      int ml = 32 * kl + 16 * (j >> 2) + 4 * l4 + (j & 3);
      o[j] = (short)f2bf(s[ml * 80 + l15 + 16 * ne]);
    }
    int ks = mc * 2 + kl;
    *reinterpret_cast<s16x8*>(
        b1F + (((size_t)bh * 8 + ks) * 5 + ne) * 64 * 8 + (size_t)l * 8) = o;
  }
}

// ---------------------------------------------------------------------------
// F2: fused {qs->frag + fourier + hq} + phi_q GEMM + exp + output GEMM.
// 1024 threads (16 waves x 32 q), grid (32 bh, 8 qc). Coalesced projF + b1F
// staging from workspace, one barrier, pure-LDS loop. (R12/R15 version)
// ---------------------------------------------------------------------------
__global__ __launch_bounds__(1024, 1) void f2_k(
    const float* __restrict__ qs, const float* __restrict__ qs_s,
    const float* __restrict__ W, const float* __restrict__ a,
    const unsigned short* __restrict__ projF,
    const unsigned short* __restrict__ b1F, float* __restrict__ out) {
  __shared__ unsigned short pf_lds[24576];   // 48 KB
  __shared__ unsigned short b1_lds[20480];   // 40 KB

  int bh = blockIdx.x, qc = blockIdx.y;
  int b = bh >> 3, h = bh & 7;
  int tid = threadIdx.x;
  int w = tid >> 6, l = tid & 63;
  int l15 = l & 15, l4 = l >> 4;
  int qb = qc * 512 + w * 32;
  const unsigned short* b1b = b1F + (size_t)bh * 8 * 5 * 64 * 8;
  float ah = a[h];

  {
    const u32x4* g1 = reinterpret_cast<const u32x4*>(projF);
    u32x4* s1 = reinterpret_cast<u32x4*>(pf_lds);
#pragma unroll
    for (int i = 0; i < 3; ++i) s1[i * 1024 + tid] = g1[i * 1024 + tid];
    const u32x4* g2 = reinterpret_cast<const u32x4*>(b1b);
    u32x4* s2 = reinterpret_cast<u32x4*>(b1_lds);
    s2[tid] = g2[tid];
    s2[1024 + tid] = g2[1024 + tid];
    if (tid < 512) s2[2048 + tid] = g2[2048 + tid];
  }

  s16x8 xq[2][3];
#pragma unroll
  for (int qt = 0; qt < 2; ++qt) {
    int qrow = qb + 16 * qt + l15;
    const float* qr = qs + ((size_t)(b * LLEN + qrow) * HH + h) * 64;
    float part = 0.f;
#pragma unroll
    for (int xs = 0; xs < 2; ++xs) {
      f32x4 u0 = *reinterpret_cast<const f32x4*>(qr + 32 * xs + 8 * l4);
      f32x4 u1 = *reinterpret_cast<const f32x4*>(qr + 32 * xs + 8 * l4 + 4);
      s16x8 fr;
#pragma unroll
      for (int i = 0; i < 4; ++i) {
        part += u0[i] * u0[i] + u1[i] * u1[i];
        fr[i] = (short)f2bf(u0[i]);
        fr[4 + i] = (short)f2bf(u1[i]);
      }
      xq[qt][xs] = fr;
    }
    part *= NORM2;
    s16x8 fx = {};
    if (l4 == 0) {
      float sv = qs_s[(size_t)b * LLEN + qrow] * TWO_PI_F;
#pragma unroll
      for (int j = 0; j < 8; ++j) {
        int dim = 8 * h + j;
        float ph = sv * W[dim & 31];
        float e = (dim < 32) ? sinf(ph) : cosf(ph);
        e *= ah;
        part += e * e;
        fx[j] = (short)f2bf(e);
      }
    }
    part += __shfl_xor(part, 16, 64);
    part += __shfl_xor(part, 32, 64);
    if (l4 == 1) fx[0] = (short)f2bf(0.5f * part + LN16);
    xq[qt][2] = fx;
  }
  __syncthreads();

  f32x4 acc3[2][5] = {};
#pragma unroll
  for (int ks = 0; ks < 8; ++ks) {
    f32x4 a0 = {}, b0 = {}, a1 = {}, b1 = {};
    __builtin_amdgcn_s_setprio(1);
#pragma unroll
    for (int xs = 0; xs < 3; ++xs) {
      s16x8 p0 = *reinterpret_cast<const s16x8*>(pf_lds + (((2 * ks) * 3 + xs) * 64 + l) * 8);
      s16x8 p1 = *reinterpret_cast<const s16x8*>(pf_lds + (((2 * ks + 1) * 3 + xs) * 64 + l) * 8);
      a0 = MFMA16(p0, xq[0][xs], a0);
      b0 = MFMA16(p1, xq[0][xs], b0);
      a1 = MFMA16(p0, xq[1][xs], a1);
      b1 = MFMA16(p1, xq[1][xs], b1);
    }
    __builtin_amdgcn_s_setprio(0);
    union { unsigned int u[4]; s16x8 s; } Pa, Pb;
    Pa.u[0] = pk2(__expf(a0[0]), __expf(a0[1]));
    Pa.u[1] = pk2(__expf(a0[2]), __expf(a0[3]));
    Pa.u[2] = pk2(__expf(b0[0]), __expf(b0[1]));
    Pa.u[3] = pk2(__expf(b0[2]), __expf(b0[3]));
    Pb.u[0] = pk2(__expf(a1[0]), __expf(a1[1]));
    Pb.u[1] = pk2(__expf(a1[2]), __expf(a1[3]));
    Pb.u[2] = pk2(__expf(b1[0]), __expf(b1[1]));
    Pb.u[3] = pk2(__expf(b1[2]), __expf(b1[3]));
    __builtin_amdgcn_s_setprio(1);
#pragma unroll
    for (int ne = 0; ne < 5; ++ne) {
      s16x8 vb = *reinterpret_cast<const s16x8*>(b1_lds + ((ks * 5 + ne) * 64 + l) * 8);
      acc3[0][ne] = MFMA16(Pa.s, vb, acc3[0][ne]);
      acc3[1][ne] = MFMA16(Pb.s, vb, acc3[1][ne]);
    }
    __builtin_amdgcn_s_setprio(0);
  }
#pragma unroll
  for (int qt = 0; qt < 2; ++qt) {
    float inv[4];
#pragma unroll
    for (int r = 0; r < 4; ++r) {
      float den = __shfl(acc3[qt][4][r], 16 * l4, 64);
      den = den < EPSV ? EPSV : den;
      inv[r] = 1.0f / den;
    }
#pragma unroll
    for (int ne = 0; ne < 4; ++ne)
#pragma unroll
      for (int r = 0; r < 4; ++r)
        out[((size_t)(b * LLEN + qb + 16 * qt + 4 * l4 + r) * HH + h) * 64 + l15 + 16 * ne] =
            acc3[qt][ne][r] * inv[r];
  }
}

// ---------------------------------------------------------------------------
extern "C" void kernel_launch(void* const* d_in, const int* in_sizes, int n_in,
                              void* d_out, int out_size, void* d_ws, size_t ws_size,
                              hipStream_t stream) {
  const float* qs   = (const float*)d_in[0];
  const float* ks   = (const float*)d_in[1];
  const float* vs   = (const float*)d_in[2];
  const float* qs_s = (const float*)d_in[3];
  const float* ks_s = (const float*)d_in[4];
  const float* W    = (const float*)d_in[5];
  const float* proj = (const float*)d_in[6];
  const float* a    = (const float*)d_in[7];
  float* out = (float*)d_out;

  char* ws = (char*)d_ws;
  unsigned short* projF = (unsigned short*)(ws + OFF_PROJF);
  unsigned short* parts = (unsigned short*)(ws + OFF_PARTS);
  unsigned short* b1F   = (unsigned short*)(ws + OFF_B1F);

  prep_projF<<<1, 256, 0, stream>>>(proj, projF);
  f1_k<<<dim3(32, NSPLIT), 1024, 0, stream>>>(ks, ks_s, vs, W, projF, parts);
  reduce_t<<<dim3(32, 4), 256, 0, stream>>>(parts, b1F);
  f2_k<<<dim3(32, 8), 1024, 0, stream>>>(qs, qs_s, W, a, projF, b1F, out);
}